// Round 3
// baseline (883.434 us; speedup 1.0000x reference)
//
#include <hip/hip_runtime.h>
#include <hip/hip_bf16.h>
#include <stdint.h>

// ---------------- problem constants ----------------
constexpr int NT = 8192;   // tokens (B*S)
constexpr int NE = 8;      // experts
constexpr int ND = 1024;   // d_model
constexpr int NH = 4096;   // hidden

constexpr int BM = 256;    // block tile M
constexpr int BN = 256;    // block tile N (8 waves: 2x4 of 128x64)
constexpr int BK = 32;     // subtile K; K-step = 64 (2 subtiles)
constexpr int KS_DN = 2;   // split-K factor for down GEMM

typedef __attribute__((ext_vector_type(8))) short short8;  // 8 bf16 (4 VGPRs)
typedef __attribute__((ext_vector_type(4))) float f32x4;

#define SB() __builtin_amdgcn_sched_barrier(0)

// ---------------- workspace layout (bytes) ----------------
constexpr size_t O_XBF  = 0;                                   // x bf16 [NT][ND]
constexpr size_t O_WUPT = O_XBF  + (size_t)NT * ND * 2;        // w_up^T bf16 [E][H][D]
constexpr size_t O_WDNT = O_WUPT + (size_t)NE * NH * ND * 2;   // w_down^T bf16 [E][D][H]
constexpr size_t O_HBUF = O_WDNT + (size_t)NE * ND * NH * 2;   // hidden bf16 [NT*2][NH]
constexpr size_t O_STOK = O_HBUF + (size_t)NT * 2 * NH * 2;    // slot -> token
constexpr size_t O_SP   = O_STOK + (size_t)NT * 2 * 4;         // slot -> gate p
constexpr size_t O_TKE  = O_SP   + (size_t)NT * 2 * 4;         // token -> top2 experts
constexpr size_t O_TKP  = O_TKE  + (size_t)NT * 2 * 4;         // token -> top2 probs
constexpr size_t O_CTRL = O_TKP  + (size_t)NT * 2 * 4;
// ctrl: cnt[16]@0 fill[16]@64 probsum[8]@128 off[16]@192 ntiles[2]@256
constexpr size_t O_TLUP = O_CTRL + 272;                        // int[160] tile list up
constexpr size_t O_TLDN = O_TLUP + 160 * 4;                    // int[160] tile list down

__device__ __forceinline__ void gl_lds16(const void* g, void* l) {
  using GP = char __attribute__((address_space(1))) *;
  using LP = char __attribute__((address_space(3))) *;
  __builtin_amdgcn_global_load_lds((GP)(uintptr_t)g, (LP)(uint32_t)(uintptr_t)l, 16, 0, 0);
}

__device__ __forceinline__ float fast_gelu(float x) {
  float u  = 0.7978845608028654f * (x + 0.044715f * x * x * x);
  float ex = __expf(2.0f * u);
  float th = 1.0f - 2.0f / (ex + 1.0f);
  return 0.5f * x * (1.0f + th);
}

// ---------------- router: logits, softmax, top2, counts; also x->bf16 ----------------
__global__ __launch_bounds__(256) void moe_router(
    const float* __restrict__ x, const float* __restrict__ rw, const float* __restrict__ rb,
    __hip_bfloat16* __restrict__ xbf,
    float* __restrict__ probs_out, int* __restrict__ topk_e, float* __restrict__ topk_p,
    int* __restrict__ cnt_ek, float* __restrict__ probsum)
{
  __shared__ float ps[NE];
  __shared__ int cs[16];
  const int tid = threadIdx.x;
  if (tid < NE) ps[tid] = 0.f;
  if (tid < 16) cs[tid] = 0;
  __syncthreads();
  const int lane = tid & 63, wv = tid >> 6;
  for (int it = 0; it < 8; ++it) {
    const int t = blockIdx.x * 4 + wv + it * 1024;
    const float* xr = x + (size_t)t * ND;
    float acc[NE] = {};
#pragma unroll 4
    for (int j = 0; j < 16; ++j) {
      const int d = j * 64 + lane;
      const float xv = xr[d];
      xbf[(size_t)t * ND + d] = __float2bfloat16(xv);
      const float* w = rw + (size_t)d * NE;
#pragma unroll
      for (int ee = 0; ee < NE; ++ee) acc[ee] += xv * w[ee];
    }
#pragma unroll
    for (int ee = 0; ee < NE; ++ee)
#pragma unroll
      for (int off = 32; off >= 1; off >>= 1)
        acc[ee] += __shfl_down(acc[ee], off, 64);
    if (lane == 0) {
      float lg[NE];
#pragma unroll
      for (int ee = 0; ee < NE; ++ee) lg[ee] = acc[ee] + rb[ee];
      float mx = lg[0];
#pragma unroll
      for (int ee = 1; ee < NE; ++ee) mx = fmaxf(mx, lg[ee]);
      float s = 0.f, pe[NE];
#pragma unroll
      for (int ee = 0; ee < NE; ++ee) { pe[ee] = __expf(lg[ee] - mx); s += pe[ee]; }
      const float inv = 1.f / s;
#pragma unroll
      for (int ee = 0; ee < NE; ++ee) {
        const float pr = pe[ee] * inv;
        probs_out[(size_t)t * NE + ee] = pr;
        atomicAdd(&ps[ee], pr);
      }
      int i1 = 0; float l1 = lg[0];
#pragma unroll
      for (int ee = 1; ee < NE; ++ee) if (lg[ee] > l1) { l1 = lg[ee]; i1 = ee; }
      int i2 = 0; float l2 = -3.0e38f;
#pragma unroll
      for (int ee = 0; ee < NE; ++ee) if (ee != i1 && lg[ee] > l2) { l2 = lg[ee]; i2 = ee; }
      const float e2 = __expf(l2 - l1);
      const float dn = 1.f + e2;
      topk_e[t * 2]     = i1;  topk_e[t * 2 + 1] = i2;
      topk_p[t * 2]     = 1.f / dn;
      topk_p[t * 2 + 1] = e2 / dn;
      atomicAdd(&cs[i1 * 2], 1);
      atomicAdd(&cs[i2 * 2 + 1], 1);
    }
  }
  __syncthreads();
  if (tid < NE) atomicAdd(&probsum[tid], ps[tid]);
  if (tid < 16) atomicAdd(&cnt_ek[tid], cs[tid]);
}

// ---------------- offsets prefix + aux loss + tile lists (256-row GEMM tiles) ----------
__global__ void moe_finalize(const int* __restrict__ cnt_ek, int* __restrict__ off_ek,
                             const float* __restrict__ probsum, float* __restrict__ aux_out,
                             int* __restrict__ ntiles, int* __restrict__ tl_up,
                             int* __restrict__ tl_dn)
{
  __shared__ int c[16], off[16], uoff[8], ucnt[8], doff[16], dcnt[16];
  const int tid = threadIdx.x;
  if (tid < 16) c[tid] = cnt_ek[tid];
  __syncthreads();
  if (tid == 0) {
    int run = 0;
    for (int i = 0; i < 16; ++i) { off[i] = run; run += c[i]; }
    int ur = 0;
    for (int e = 0; e < NE; ++e) {
      ucnt[e] = (c[2 * e] + c[2 * e + 1] + BM - 1) / BM;
      uoff[e] = ur; ur += ucnt[e];
    }
    ntiles[0] = ur;
    int dr = 0;
    for (int i = 0; i < 16; ++i) {
      dcnt[i] = (c[i] + BM - 1) / BM;
      doff[i] = dr; dr += dcnt[i];
    }
    ntiles[1] = dr;
    float aux = 0.f;
    for (int e = 0; e < NE; ++e) {
      float frac = (float)(c[2 * e] + c[2 * e + 1]) / (float)(NT * 2);
      aux += frac * (probsum[e] / (float)NT);
    }
    aux_out[0] = (float)NE * aux * 0.01f;
  }
  __syncthreads();
  if (tid < 16) off_ek[tid] = off[tid];
  if (tid < 8)
    for (int mb = 0; mb < ucnt[tid]; ++mb) tl_up[uoff[tid] + mb] = (tid << 16) | mb;
  if (tid >= 32 && tid < 48) {
    const int i = tid - 32;
    for (int mb = 0; mb < dcnt[i]; ++mb) tl_dn[doff[i] + mb] = (i << 16) | mb;
  }
}

// ---------------- scatter: per-block LDS histogram, 16 global atomics/block ----------
__global__ __launch_bounds__(256) void moe_scatter(
    const int* __restrict__ topk_e, const float* __restrict__ topk_p,
    const int* __restrict__ off_ek, int* __restrict__ fill_ek,
    int* __restrict__ slot_token, float* __restrict__ slot_p)
{
  __shared__ int lc[16], gb[16], offs[16];
  const int tid = threadIdx.x;
  if (tid < 16) lc[tid] = 0;
  __syncthreads();
  const int t = blockIdx.x * 256 + tid;
  const int id0 = topk_e[t * 2] * 2;
  const int id1 = topk_e[t * 2 + 1] * 2 + 1;
  atomicAdd(&lc[id0], 1);
  atomicAdd(&lc[id1], 1);
  __syncthreads();
  if (tid < 16) {
    gb[tid] = atomicAdd(&fill_ek[tid], lc[tid]);
    offs[tid] = off_ek[tid];
    lc[tid] = 0;
  }
  __syncthreads();
  {
    const int r = atomicAdd(&lc[id0], 1);
    const int slot = offs[id0] + gb[id0] + r;
    slot_token[slot] = t;
    slot_p[slot] = topk_p[t * 2];
  }
  {
    const int r = atomicAdd(&lc[id1], 1);
    const int slot = offs[id1] + gb[id1] + r;
    slot_token[slot] = t;
    slot_p[slot] = topk_p[t * 2 + 1];
  }
}

// ---------------- transpose+cast: in fp32 [E][A][B] -> out bf16 [E][B][A] ----------------
__global__ __launch_bounds__(256) void moe_transpose_cast(
    const float* __restrict__ in, __hip_bfloat16* __restrict__ outp, int Adim, int Bdim)
{
  __shared__ unsigned short tile[64 * 66];
  const int e = blockIdx.z;
  const int b0 = blockIdx.x * 64, a0 = blockIdx.y * 64;
  const float* ip = in + (size_t)e * Adim * Bdim + (size_t)a0 * Bdim + b0;
  const int c4 = (threadIdx.x & 15) * 4;
  const int r0 = threadIdx.x >> 4;
#pragma unroll
  for (int i = 0; i < 4; ++i) {
    const int r = r0 + i * 16;
    const float4 v = *(const float4*)(ip + (size_t)r * Bdim + c4);
    ushort4 u;
    u.x = __hip_bfloat16_raw(__float2bfloat16(v.x)).x;
    u.y = __hip_bfloat16_raw(__float2bfloat16(v.y)).x;
    u.z = __hip_bfloat16_raw(__float2bfloat16(v.z)).x;
    u.w = __hip_bfloat16_raw(__float2bfloat16(v.w)).x;
    *(ushort4*)&tile[r * 66 + c4] = u;
  }
  __syncthreads();
  unsigned short* op = (unsigned short*)outp + (size_t)e * Bdim * Adim + (size_t)b0 * Adim + a0;
  const int cc  = threadIdx.x >> 2;
  const int rr0 = (threadIdx.x & 3) * 16;
  unsigned short u[16];
#pragma unroll
  for (int i = 0; i < 16; ++i) u[i] = tile[(rr0 + i) * 66 + cc];
  *(short8*)(op + (size_t)cc * Adim + rr0)     = *(short8*)&u[0];
  *(short8*)(op + (size_t)cc * Adim + rr0 + 8) = *(short8*)&u[8];
}

// ============================================================================
// Grouped GEMMs (this round: fine-phase interleave, m201-style):
//   256x256 tile, 8 waves (2Mx4N; 128x64/wave), K-step 64 = 2 subtiles of 32.
//   LDS: 4 subtile buffers = 2 pairs, double-buffered at K-step granularity
//   (128 KB). Per K-step: ONE vmcnt(0)+s_barrier, then stage the NEXT K-step
//   (8 gl_lds, drained a full iteration later -> latency hidden, no loads
//   pending at the wait), then 8 fine phases: {ds_reads for next quadrant}
//   SB {8 MFMA current quadrant, setprio-wrapped} SB. This pins per-wave
//   read||MFMA interleave so LDS service hides under the MFMA pipe (the
//   round-2 coarse read-burst/MFMA-burst alternation measured 23% MfmaUtil).
// Race proof: reads use pair p, stage writes pair 1-p; a wave passes barrier_j
// only after its MFMAs consumed all pair-(1-p) reads of iter j-1 (dataflow).
// Chunk XOR swizzle (measured 0 conflicts): slot (row,c) holds chunk
// c ^ ((row>>1)&3), 64B row stride.
// ============================================================================

#define MFMA8(aX, aY, bA, mtX, mtY)                                            \
  __builtin_amdgcn_s_setprio(1);                                               \
  _Pragma("unroll")                                                            \
  for (int nt = 0; nt < 4; ++nt)                                               \
    acc[mtX][nt] = __builtin_amdgcn_mfma_f32_16x16x32_bf16(aX, bA[nt], acc[mtX][nt], 0, 0, 0); \
  _Pragma("unroll")                                                            \
  for (int nt = 0; nt < 4; ++nt)                                               \
    acc[mtY][nt] = __builtin_amdgcn_mfma_f32_16x16x32_bf16(aY, bA[nt], acc[mtY][nt], 0, 0, 0); \
  __builtin_amdgcn_s_setprio(0);

// ---------------- grouped GEMM 1: H = gelu(X_sel @ w_up + b_up) ----------------
__global__ __launch_bounds__(512, 2) void moe_gemm_up(
    const __hip_bfloat16* __restrict__ xbf,
    const __hip_bfloat16* __restrict__ wupT,   // [E][H][D]
    const float* __restrict__ b_up,
    const int* __restrict__ slot_token,
    const int* __restrict__ cnt_ek, const int* __restrict__ off_ek,
    const int* __restrict__ ntiles, const int* __restrict__ tl_up,
    __hip_bfloat16* __restrict__ hbuf)          // [NT*2][NH]
{
  if ((int)blockIdx.y >= ntiles[0]) return;
  const int tl = tl_up[blockIdx.y];
  const int e = tl >> 16, mb = tl & 0xffff;
  const int cnt = cnt_ek[2 * e] + cnt_ek[2 * e + 1];
  const int base = off_ek[2 * e];
  const int m0 = mb * BM;
  const int n0 = blockIdx.x * BN;
  const int valid = (cnt - m0 < BM) ? (cnt - m0) : BM;

  __shared__ __align__(16) __hip_bfloat16 As[4][BM * BK];   // 64 KB
  __shared__ __align__(16) __hip_bfloat16 Bs[4][BN * BK];   // 64 KB

  const int tid = threadIdx.x;
  const int lane = tid & 63, wv = tid >> 6;

  // staging addressing: thread covers (row = tid>>2 [+128], chunk = tid&3)
  const int r0c = tid >> 2;
  const int k0c = ((tid & 3) ^ ((r0c >> 1) & 3)) * 8;
  const int r1c = r0c + 128;
  const int k1c = ((tid & 3) ^ ((r1c >> 1) & 3)) * 8;
  int srA0 = m0 + r0c; if (srA0 >= cnt) srA0 = cnt - 1;
  int srA1 = m0 + r1c; if (srA1 >= cnt) srA1 = cnt - 1;
  const __hip_bfloat16* gA0 = xbf + (size_t)slot_token[base + srA0] * ND + k0c;
  const __hip_bfloat16* gA1 = xbf + (size_t)slot_token[base + srA1] * ND + k1c;
  const __hip_bfloat16* gB0 = wupT + ((size_t)e * NH + n0 + r0c) * ND + k0c;
  const __hip_bfloat16* gB1 = wupT + ((size_t)e * NH + n0 + r1c) * ND + k1c;

  char* sA0 = (char*)&As[0][0] + tid * 16;  char* sB0 = (char*)&Bs[0][0] + tid * 16;
  char* sA1 = (char*)&As[1][0] + tid * 16;  char* sB1 = (char*)&Bs[1][0] + tid * 16;
  char* sA2 = (char*)&As[2][0] + tid * 16;  char* sB2 = (char*)&Bs[2][0] + tid * 16;
  char* sA3 = (char*)&As[3][0] + tid * 16;  char* sB3 = (char*)&Bs[3][0] + tid * 16;

  // per-wave swizzled read bases
  const int wm = (wv >> 2) * 128, wn = (wv & 3) * 64;
  const int l15 = lane & 15, q = lane >> 4;
  const int ssw = (q ^ ((l15 >> 1) & 3)) * 16;
  const char* rA0 = (const char*)&As[0][0] + (wm + l15) * 64 + ssw;
  const char* rA1 = (const char*)&As[1][0] + (wm + l15) * 64 + ssw;
  const char* rA2 = (const char*)&As[2][0] + (wm + l15) * 64 + ssw;
  const char* rA3 = (const char*)&As[3][0] + (wm + l15) * 64 + ssw;
  const char* rB0 = (const char*)&Bs[0][0] + (wn + l15) * 64 + ssw;
  const char* rB1 = (const char*)&Bs[1][0] + (wn + l15) * 64 + ssw;
  const char* rB2 = (const char*)&Bs[2][0] + (wn + l15) * 64 + ssw;
  const char* rB3 = (const char*)&Bs[3][0] + (wn + l15) * 64 + ssw;

  f32x4 acc[8][4] = {};

  // stage one K-step (2 subtiles) into buffer pair {xA0,xA1}
  auto STAGEP = [&](char* xA0, char* xB0, char* xA1, char* xB1, int kk) {
    gl_lds16(gA0 + kk, xA0);        gl_lds16(gA1 + kk, xA0 + 8192);
    gl_lds16(gB0 + kk, xB0);        gl_lds16(gB1 + kk, xB0 + 8192);
    gl_lds16(gA0 + kk + BK, xA1);   gl_lds16(gA1 + kk + BK, xA1 + 8192);
    gl_lds16(gB0 + kk + BK, xB1);   gl_lds16(gB1 + kk + BK, xB1 + 8192);
  };

  // one K-step: read pair (pA0/pB0 = K low 32, pA1/pB1 = high 32),
  // stage next K-step into the other pair; 8 fine phases.
  auto KSTEP = [&](const char* pA0, const char* pB0, const char* pA1, const char* pB1,
                   char* xA0, char* xB0, char* xA1, char* xB1, int knext, bool do_stage) {
    asm volatile("s_waitcnt vmcnt(0)" ::: "memory");   // own loads of current pair done
    __builtin_amdgcn_s_barrier();                      // all waves' loads done; prev pair free
    if (do_stage) STAGEP(xA0, xB0, xA1, xB1, knext);
    short8 b0[4], b1[4];
    short8 a00, a01, a02, a03, a04, a05, a06, a07;
    short8 a10, a11, a12, a13, a14, a15, a16, a17;
    // pre-group: subtile0 B frags + first A pair
#pragma unroll
    for (int i = 0; i < 4; ++i) b0[i] = *(const short8*)(pB0 + i * 1024);
    a00 = *(const short8*)(pA0);
    a01 = *(const short8*)(pA0 + 1024);
    SB();
    a02 = *(const short8*)(pA0 + 2048); a03 = *(const short8*)(pA0 + 3072); SB();
    MFMA8(a00, a01, b0, 0, 1); SB();
    a04 = *(const short8*)(pA0 + 4096); a05 = *(const short8*)(pA0 + 5120); SB();
    MFMA8(a02, a03, b0, 2, 3); SB();
    a06 = *(const short8*)(pA0 + 6144); a07 = *(const short8*)(pA0 + 7168); SB();
    MFMA8(a04, a05, b0, 4, 5); SB();
#pragma unroll
    for (int i = 0; i < 4; ++i) b1[i] = *(const short8*)(pB1 + i * 1024);
    a10 = *(const short8*)(pA1);
    a11 = *(const short8*)(pA1 + 1024);
    SB();
    MFMA8(a06, a07, b0, 6, 7); SB();
    a12 = *(const short8*)(pA1 + 2048); a13 = *(const short8*)(pA1 + 3072); SB();
    MFMA8(a10, a11, b1, 0, 1); SB();
    a14 = *(const short8*)(pA1 + 4096); a15 = *(const short8*)(pA1 + 5120); SB();
    MFMA8(a12, a13, b1, 2, 3); SB();
    a16 = *(const short8*)(pA1 + 6144); a17 = *(const short8*)(pA1 + 7168); SB();
    MFMA8(a14, a15, b1, 4, 5); SB();
    MFMA8(a16, a17, b1, 6, 7);
  };

  constexpr int NK = ND / 64;   // 16 K-steps
  STAGEP(sA0, sB0, sA1, sB1, 0);
#pragma unroll 1
  for (int j = 0; j < NK; j += 2) {
    KSTEP(rA0, rB0, rA1, rB1, sA2, sB2, sA3, sB3, (j + 1) * 64, j + 1 < NK);
    KSTEP(rA2, rB2, rA3, rB3, sA0, sB0, sA1, sB1, (j + 2) * 64, j + 2 < NK);
  }

  float bias[4];
#pragma unroll
  for (int nt = 0; nt < 4; ++nt) bias[nt] = b_up[e * NH + n0 + wn + nt * 16 + l15];
#pragma unroll
  for (int mt = 0; mt < 8; ++mt) {
#pragma unroll
    for (int rr = 0; rr < 4; ++rr) {
      const int row = wm + mt * 16 + q * 4 + rr;
      if (row < valid) {
        const size_t rbase = (size_t)(base + m0 + row) * NH;
#pragma unroll
        for (int nt = 0; nt < 4; ++nt) {
          const int col = n0 + wn + nt * 16 + l15;
          hbuf[rbase + col] = __float2bfloat16(fast_gelu(acc[mt][nt][rr] + bias[nt]));
        }
      }
    }
  }
}

// ---------------- grouped GEMM 2: out += p * (H @ w_down + b_down) ----------------
// split-K=2 over NH (grid.z); bias added by ks==0 half; fp32 atomics.
__global__ __launch_bounds__(512, 2) void moe_gemm_down(
    const __hip_bfloat16* __restrict__ hbuf,
    const __hip_bfloat16* __restrict__ wdnT,   // [E][D][H]
    const float* __restrict__ b_down,
    const int* __restrict__ slot_token, const float* __restrict__ slot_p,
    const int* __restrict__ cnt_ek, const int* __restrict__ off_ek,
    const int* __restrict__ ntiles, const int* __restrict__ tl_dn,
    float* __restrict__ out)
{
  if ((int)blockIdx.y >= ntiles[1]) return;
  const int tl = tl_dn[blockIdx.y];
  const int id = tl >> 16, mb = tl & 0xffff;
  const int e = id >> 1;
  const int cnt = cnt_ek[id];
  const int base = off_ek[id];
  const int m0 = mb * BM;
  const int n0 = blockIdx.x * BN;
  const int valid = (cnt - m0 < BM) ? (cnt - m0) : BM;
  const int ks = blockIdx.z;
  const int k_beg = ks * (NH / KS_DN);

  __shared__ __align__(16) __hip_bfloat16 As[4][BM * BK];   // 64 KB
  __shared__ __align__(16) __hip_bfloat16 Bs[4][BN * BK];   // 64 KB

  const int tid = threadIdx.x;
  const int lane = tid & 63, wv = tid >> 6;

  const int r0c = tid >> 2;
  const int k0c = ((tid & 3) ^ ((r0c >> 1) & 3)) * 8;
  const int r1c = r0c + 128;
  const int k1c = ((tid & 3) ^ ((r1c >> 1) & 3)) * 8;
  int srA0 = m0 + r0c; if (srA0 >= cnt) srA0 = cnt - 1;
  int srA1 = m0 + r1c; if (srA1 >= cnt) srA1 = cnt - 1;
  const __hip_bfloat16* gA0 = hbuf + (size_t)(base + srA0) * NH + k0c;
  const __hip_bfloat16* gA1 = hbuf + (size_t)(base + srA1) * NH + k1c;
  const __hip_bfloat16* gB0 = wdnT + ((size_t)e * ND + n0 + r0c) * NH + k0c;
  const __hip_bfloat16* gB1 = wdnT + ((size_t)e * ND + n0 + r1c) * NH + k1c;

  char* sA0 = (char*)&As[0][0] + tid * 16;  char* sB0 = (char*)&Bs[0][0] + tid * 16;
  char* sA1 = (char*)&As[1][0] + tid * 16;  char* sB1 = (char*)&Bs[1][0] + tid * 16;
  char* sA2 = (char*)&As[2][0] + tid * 16;  char* sB2 = (char*)&Bs[2][0] + tid * 16;
  char* sA3 = (char*)&As[3][0] + tid * 16;  char* sB3 = (char*)&Bs[3][0] + tid * 16;

  const int wm = (wv >> 2) * 128, wn = (wv & 3) * 64;
  const int l15 = lane & 15, q = lane >> 4;
  const int ssw = (q ^ ((l15 >> 1) & 3)) * 16;
  const char* rA0 = (const char*)&As[0][0] + (wm + l15) * 64 + ssw;
  const char* rA1 = (const char*)&As[1][0] + (wm + l15) * 64 + ssw;
  const char* rA2 = (const char*)&As[2][0] + (wm + l15) * 64 + ssw;
  const char* rA3 = (const char*)&As[3][0] + (wm + l15) * 64 + ssw;
  const char* rB0 = (const char*)&Bs[0][0] + (wn + l15) * 64 + ssw;
  const char* rB1 = (const char*)&Bs[1][0] + (wn + l15) * 64 + ssw;
  const char* rB2 = (const char*)&Bs[2][0] + (wn + l15) * 64 + ssw;
  const char* rB3 = (const char*)&Bs[3][0] + (wn + l15) * 64 + ssw;

  f32x4 acc[8][4] = {};

  auto STAGEP = [&](char* xA0, char* xB0, char* xA1, char* xB1, int kk) {
    gl_lds16(gA0 + kk, xA0);        gl_lds16(gA1 + kk, xA0 + 8192);
    gl_lds16(gB0 + kk, xB0);        gl_lds16(gB1 + kk, xB0 + 8192);
    gl_lds16(gA0 + kk + BK, xA1);   gl_lds16(gA1 + kk + BK, xA1 + 8192);
    gl_lds16(gB0 + kk + BK, xB1);   gl_lds16(gB1 + kk + BK, xB1 + 8192);
  };

  auto KSTEP = [&](const char* pA0, const char* pB0, const char* pA1, const char* pB1,
                   char* xA0, char* xB0, char* xA1, char* xB1, int knext, bool do_stage) {
    asm volatile("s_waitcnt vmcnt(0)" ::: "memory");
    __builtin_amdgcn_s_barrier();
    if (do_stage) STAGEP(xA0, xB0, xA1, xB1, knext);
    short8 b0[4], b1[4];
    short8 a00, a01, a02, a03, a04, a05, a06, a07;
    short8 a10, a11, a12, a13, a14, a15, a16, a17;
#pragma unroll
    for (int i = 0; i < 4; ++i) b0[i] = *(const short8*)(pB0 + i * 1024);
    a00 = *(const short8*)(pA0);
    a01 = *(const short8*)(pA0 + 1024);
    SB();
    a02 = *(const short8*)(pA0 + 2048); a03 = *(const short8*)(pA0 + 3072); SB();
    MFMA8(a00, a01, b0, 0, 1); SB();
    a04 = *(const short8*)(pA0 + 4096); a05 = *(const short8*)(pA0 + 5120); SB();
    MFMA8(a02, a03, b0, 2, 3); SB();
    a06 = *(const short8*)(pA0 + 6144); a07 = *(const short8*)(pA0 + 7168); SB();
    MFMA8(a04, a05, b0, 4, 5); SB();
#pragma unroll
    for (int i = 0; i < 4; ++i) b1[i] = *(const short8*)(pB1 + i * 1024);
    a10 = *(const short8*)(pA1);
    a11 = *(const short8*)(pA1 + 1024);
    SB();
    MFMA8(a06, a07, b0, 6, 7); SB();
    a12 = *(const short8*)(pA1 + 2048); a13 = *(const short8*)(pA1 + 3072); SB();
    MFMA8(a10, a11, b1, 0, 1); SB();
    a14 = *(const short8*)(pA1 + 4096); a15 = *(const short8*)(pA1 + 5120); SB();
    MFMA8(a12, a13, b1, 2, 3); SB();
    a16 = *(const short8*)(pA1 + 6144); a17 = *(const short8*)(pA1 + 7168); SB();
    MFMA8(a14, a15, b1, 4, 5); SB();
    MFMA8(a16, a17, b1, 6, 7);
  };

  constexpr int NK = (NH / KS_DN) / 64;   // 32 K-steps
  STAGEP(sA0, sB0, sA1, sB1, k_beg);
#pragma unroll 1
  for (int j = 0; j < NK; j += 2) {
    KSTEP(rA0, rB0, rA1, rB1, sA2, sB2, sA3, sB3, k_beg + (j + 1) * 64, j + 1 < NK);
    KSTEP(rA2, rB2, rA3, rB3, sA0, sB0, sA1, sB1, k_beg + (j + 2) * 64, j + 2 < NK);
  }

  float bias[4];
#pragma unroll
  for (int nt = 0; nt < 4; ++nt)
    bias[nt] = (ks == 0) ? b_down[e * ND + n0 + wn + nt * 16 + l15] : 0.f;
#pragma unroll
  for (int mt = 0; mt < 8; ++mt) {
#pragma unroll
    for (int rr = 0; rr < 4; ++rr) {
      const int row = wm + mt * 16 + q * 4 + rr;
      if (row < valid) {
        const int slot = base + m0 + row;
        const int tok = slot_token[slot];
        const float p = slot_p[slot];
        const size_t obase = (size_t)tok * ND;
#pragma unroll
        for (int nt = 0; nt < 4; ++nt) {
          const int col = n0 + wn + nt * 16 + l15;
          atomicAdd(&out[obase + col], (acc[mt][nt][rr] + bias[nt]) * p);
        }
      }
    }
  }
}

// ---------------- launch ----------------
extern "C" void kernel_launch(void* const* d_in, const int* in_sizes, int n_in,
                              void* d_out, int out_size, void* d_ws, size_t ws_size,
                              hipStream_t stream) {
  (void)in_sizes; (void)n_in; (void)out_size; (void)ws_size;
  const float* x   = (const float*)d_in[0];
  const float* rw  = (const float*)d_in[1];
  const float* rb  = (const float*)d_in[2];
  const float* wup = (const float*)d_in[3];
  const float* bup = (const float*)d_in[4];
  const float* wdn = (const float*)d_in[5];
  const float* bdn = (const float*)d_in[6];
  float* out = (float*)d_out;

  char* ws = (char*)d_ws;
  __hip_bfloat16* xbf  = (__hip_bfloat16*)(ws + O_XBF);
  __hip_bfloat16* wupT = (__hip_bfloat16*)(ws + O_WUPT);
  __hip_bfloat16* wdnT = (__hip_bfloat16*)(ws + O_WDNT);
  __hip_bfloat16* hbuf = (__hip_bfloat16*)(ws + O_HBUF);
  int*   slot_token = (int*)(ws + O_STOK);
  float* slot_p     = (float*)(ws + O_SP);
  int*   topk_e     = (int*)(ws + O_TKE);
  float* topk_p     = (float*)(ws + O_TKP);
  int*   cnt_ek  = (int*)(ws + O_CTRL);
  int*   fill_ek = (int*)(ws + O_CTRL + 64);
  float* probsum = (float*)(ws + O_CTRL + 128);
  int*   off_ek  = (int*)(ws + O_CTRL + 192);
  int*   ntiles  = (int*)(ws + O_CTRL + 256);
  int*   tl_up   = (int*)(ws + O_TLUP);
  int*   tl_dn   = (int*)(ws + O_TLDN);

  hipMemsetAsync(ws + O_CTRL, 0, 272, stream);
  hipMemsetAsync(out, 0, (size_t)NT * ND * sizeof(float), stream);  // down-GEMM atomicAdd target

  // weight transposes (independent of router)
  moe_transpose_cast<<<dim3(NH / 64, ND / 64, NE), 256, 0, stream>>>(wup, wupT, ND, NH);
  moe_transpose_cast<<<dim3(ND / 64, NH / 64, NE), 256, 0, stream>>>(wdn, wdnT, NH, ND);

  // router (+ x->bf16), aux/offsets/tile-lists, scatter
  moe_router<<<256, 256, 0, stream>>>(x, rw, rb, xbf, out + (size_t)NT * ND + 1,
                                      topk_e, topk_p, cnt_ek, probsum);
  moe_finalize<<<1, 64, 0, stream>>>(cnt_ek, off_ek, probsum, out + (size_t)NT * ND,
                                     ntiles, tl_up, tl_dn);
  moe_scatter<<<NT / 256, 256, 0, stream>>>(topk_e, topk_p, off_ek, fill_ek, slot_token, slot_p);

  // grouped GEMMs. Worst-case tile counts: up <= ceil(16384/256)+7 = 71,
  // down <= 64+15 = 79; blocks early-exit past device-side tile counts.
  moe_gemm_up<<<dim3(NH / BN, 72, 1), 512, 0, stream>>>(
      xbf, wupT, bup, slot_token, cnt_ek, off_ek, ntiles, tl_up, hbuf);
  moe_gemm_down<<<dim3(ND / BN, 80, KS_DN), 512, 0, stream>>>(
      hbuf, wdnT, bdn, slot_token, slot_p, cnt_ek, off_ek, ntiles, tl_dn, out);
}